// Round 7
// baseline (707.960 us; speedup 1.0000x reference)
//
#include <hip/hip_runtime.h>
#include <cstdint>

#define N_GRAPHS 20000
#define SCAN_CHUNK 2048

// ---------------- degree (4-edge batched atomics) ----------------
__global__ void count_in_deg(const int* __restrict__ dst, int* __restrict__ cnt, int E) {
  int i = blockIdx.x * blockDim.x + threadIdx.x;
  int stride = gridDim.x * blockDim.x;
  for (int base = i; base < E; base += 4 * stride) {
    int e1 = base + stride, e2 = base + 2 * stride, e3 = base + 3 * stride;
    bool b1 = e1 < E, b2 = e2 < E, b3 = e3 < E;
    int d0 = dst[base];
    int d1 = b1 ? dst[e1] : 0;
    int d2 = b2 ? dst[e2] : 0;
    int d3 = b3 ? dst[e3] : 0;
    atomicAdd(&cnt[d0], 1);
    if (b1) atomicAdd(&cnt[d1], 1);
    if (b2) atomicAdd(&cnt[d2], 1);
    if (b3) atomicAdd(&cnt[d3], 1);
  }
}

__global__ void inv_sqrt_deg(const int* __restrict__ cnt, float* __restrict__ isq, int N) {
  int i = blockIdx.x * blockDim.x + threadIdx.x;
  if (i < N) isq[i] = rsqrtf((float)(cnt[i] + 1));
}

// ---------------- prefix scan (exclusive) of cnt[N] -> rs[N+1] ----------------
__global__ __launch_bounds__(256) void scan1(const int* __restrict__ cnt, int* __restrict__ rs,
                                             int* __restrict__ bsum, int N) {
  __shared__ int lds[256];
  int t = threadIdx.x;
  int base = blockIdx.x * SCAN_CHUNK + t * 8;
  int v[8];
  int s = 0;
#pragma unroll
  for (int i = 0; i < 8; ++i) {
    v[i] = (base + i < N) ? cnt[base + i] : 0;
    s += v[i];
  }
  lds[t] = s;
  __syncthreads();
  for (int off = 1; off < 256; off <<= 1) {
    int x = (t >= off) ? lds[t - off] : 0;
    __syncthreads();
    lds[t] += x;
    __syncthreads();
  }
  if (t == 255) bsum[blockIdx.x] = lds[255];
  int run = (t > 0) ? lds[t - 1] : 0;
#pragma unroll
  for (int i = 0; i < 8; ++i) {
    if (base + i <= N) rs[base + i] = run;
    run += v[i];
  }
}

__global__ __launch_bounds__(256) void scan2(int* __restrict__ bsum, int nb) {
  __shared__ int lds[256];
  int t = threadIdx.x;
  lds[t] = (t < nb) ? bsum[t] : 0;
  __syncthreads();
  for (int off = 1; off < 256; off <<= 1) {
    int x = (t >= off) ? lds[t - off] : 0;
    __syncthreads();
    lds[t] += x;
    __syncthreads();
  }
  if (t < nb) bsum[t] = (t > 0) ? lds[t - 1] : 0;  // exclusive
}

// scan3 also seeds ptr[] = rs[] (running CSR write cursor)
__global__ void scan3(int* __restrict__ rs, const int* __restrict__ bsum,
                      int* __restrict__ ptr, int Np1) {
  int i = blockIdx.x * blockDim.x + threadIdx.x;
  if (i < Np1) {
    int v = rs[i] + bsum[i / SCAN_CHUNK];
    rs[i] = v;
    if (i < Np1 - 1) ptr[i] = v;
  }
}

// ---------------- CSR fill: one random atomic per edge, 4-edge batched ----------------
__global__ void csr_fill(const int* __restrict__ src, const int* __restrict__ dst,
                         int* __restrict__ ptr, int* __restrict__ csr, int E) {
  int i = blockIdx.x * blockDim.x + threadIdx.x;
  int stride = gridDim.x * blockDim.x;
  for (int base = i; base < E; base += 4 * stride) {
    int e1 = base + stride, e2 = base + 2 * stride, e3 = base + 3 * stride;
    bool b1 = e1 < E, b2 = e2 < E, b3 = e3 < E;
    int d0 = dst[base];
    int d1 = b1 ? dst[e1] : 0;
    int d2 = b2 ? dst[e2] : 0;
    int d3 = b3 ? dst[e3] : 0;
    int s0 = src[base];
    int s1 = b1 ? src[e1] : 0;
    int s2 = b2 ? src[e2] : 0;
    int s3 = b3 ? src[e3] : 0;
    int p0 = atomicAdd(&ptr[d0], 1);
    int p1 = b1 ? atomicAdd(&ptr[d1], 1) : 0;
    int p2 = b2 ? atomicAdd(&ptr[d2], 1) : 0;
    int p3 = b3 ? atomicAdd(&ptr[d3], 1) : 0;
    csr[p0] = s0;
    if (b1) csr[p1] = s1;
    if (b2) csr[p2] = s2;
    if (b3) csr[p3] = s3;
  }
}

// ---------------- node GEMM + row scale: out[r,:] = (in[r,:] @ W) * isq[r] ----------------
__global__ __launch_bounds__(256) void gemm_n64(const float* __restrict__ in,
                                                const float* __restrict__ W,
                                                const float* __restrict__ isq,
                                                float* __restrict__ out, int N) {
  __shared__ float Wl[64 * 64];
  __shared__ float Rl[64 * 65];
  int tid = threadIdx.x;
#pragma unroll
  for (int v = 0; v < 4; ++v) {
    int u = tid + v * 256;
    *(float4*)&Wl[u * 4] = *(const float4*)&W[u * 4];
  }
  long base_row = (long)blockIdx.x * 64;
#pragma unroll
  for (int v = 0; v < 4; ++v) {
    int u = tid + v * 256;
    int r = u >> 4;
    int k = (u & 15) * 4;
    long row = base_row + r;
    float4 val = make_float4(0.f, 0.f, 0.f, 0.f);
    if (row < N) val = *(const float4*)&in[row * 64 + k];
    *(float4*)&Rl[r * 65 + k] = val;
  }
  __syncthreads();
  int r = tid >> 2;
  int c0 = (tid & 3) * 16;
  float acc[16];
#pragma unroll
  for (int j = 0; j < 16; ++j) acc[j] = 0.f;
#pragma unroll 4
  for (int k = 0; k < 64; ++k) {
    float a = Rl[r * 65 + k];
#pragma unroll
    for (int j = 0; j < 16; ++j) acc[j] += a * Wl[k * 64 + c0 + j];
  }
  long row = base_row + r;
  if (row < N) {
    float sc = isq[row];
#pragma unroll
    for (int v = 0; v < 4; ++v) {
      *(float4*)&out[row * 64 + c0 + v * 4] =
          make_float4(acc[v * 4] * sc, acc[v * 4 + 1] * sc, acc[v * 4 + 2] * sc,
                      acc[v * 4 + 3] * sc);
    }
  }
}

// ------- gather conv: out[d] = relu(isq[d]*(sum_{s in N(d)} hp[s] + hp[d]) + b) -------
__global__ __launch_bounds__(256) void gather_conv(const float* __restrict__ hp,
                                                   const int* __restrict__ csr,
                                                   const int* __restrict__ rs,
                                                   const float* __restrict__ isq,
                                                   const float* __restrict__ bias,
                                                   float* __restrict__ out, int N) {
  int lane = threadIdx.x & 63;
  int sub = lane & 15;   // channel quad within row
  int grp = lane >> 4;   // dst group within wave
  int wid = (blockIdx.x * blockDim.x + threadIdx.x) >> 6;
  float4 bv = *(const float4*)&bias[sub * 4];
  long d0 = (long)wid * 4;
  if (d0 >= N) return;
  int d = (int)d0 + grp;
  bool vd = d < N;
  int dd = vd ? d : N - 1;
  int jj = rs[dd];
  int je = vd ? rs[dd + 1] : jj;
  float4 ac = make_float4(0.f, 0.f, 0.f, 0.f);
  if (vd) ac = *(const float4*)&hp[(long)dd * 64 + sub * 4];
  while (__any(jj < je)) {
    bool a0 = jj < je;
    bool a1 = jj + 1 < je;
    bool a2 = jj + 2 < je;
    bool a3 = jj + 3 < je;
    int s0 = csr[jj];
    int s1 = csr[jj + 1];
    int s2 = csr[jj + 2];
    int s3 = csr[jj + 3];
    float4 v0 = make_float4(0.f, 0.f, 0.f, 0.f);
    float4 v1 = make_float4(0.f, 0.f, 0.f, 0.f);
    float4 v2 = make_float4(0.f, 0.f, 0.f, 0.f);
    float4 v3 = make_float4(0.f, 0.f, 0.f, 0.f);
    if (a0) v0 = *(const float4*)&hp[(long)s0 * 64 + sub * 4];
    if (a1) v1 = *(const float4*)&hp[(long)s1 * 64 + sub * 4];
    if (a2) v2 = *(const float4*)&hp[(long)s2 * 64 + sub * 4];
    if (a3) v3 = *(const float4*)&hp[(long)s3 * 64 + sub * 4];
    ac.x += (v0.x + v1.x) + (v2.x + v3.x);
    ac.y += (v0.y + v1.y) + (v2.y + v3.y);
    ac.z += (v0.z + v1.z) + (v2.z + v3.z);
    ac.w += (v0.w + v1.w) + (v2.w + v3.w);
    jj += 4;
  }
  if (vd) {
    float id = isq[d];
    float4 r;
    r.x = fmaxf(fmaf(ac.x, id, bv.x), 0.f);
    r.y = fmaxf(fmaf(ac.y, id, bv.y), 0.f);
    r.z = fmaxf(fmaf(ac.z, id, bv.z), 0.f);
    r.w = fmaxf(fmaf(ac.w, id, bv.w), 0.f);
    *(float4*)&out[(long)d * 64 + sub * 4] = r;
  }
}

// ---------------- graph segment offsets from sorted batch_idx ----------------
__global__ void seg_offsets(const int* __restrict__ batch, int* __restrict__ off, int N, int G) {
  int i = blockIdx.x * blockDim.x + threadIdx.x;
  if (i >= N) return;
  int b = batch[i];
  if (i == 0) {
    for (int g = 0; g <= b; ++g) off[g] = 0;
  } else {
    int pb = batch[i - 1];
    for (int g = pb + 1; g <= b; ++g) off[g] = i;
  }
  if (i == N - 1) {
    for (int g = b + 1; g <= G; ++g) off[g] = N;
  }
}

// ---------------- mean pool: wave per graph, 4 independent partial sums ----------------
__global__ void pool_mean(const float* __restrict__ e2, const int* __restrict__ off,
                          float* __restrict__ ge, int G) {
  int lane = threadIdx.x & 63;
  int wid = (blockIdx.x * blockDim.x + threadIdx.x) >> 6;
  int nw = (gridDim.x * blockDim.x) >> 6;
  for (int g = wid; g < G; g += nw) {
    int s = off[g];
    int e = off[g + 1];
    float s0 = 0.f, s1 = 0.f, s2 = 0.f, s3 = 0.f;
    int n = s;
    for (; n + 3 < e; n += 4) {
      s0 += e2[(long)n * 64 + lane];
      s1 += e2[(long)(n + 1) * 64 + lane];
      s2 += e2[(long)(n + 2) * 64 + lane];
      s3 += e2[(long)(n + 3) * 64 + lane];
    }
    for (; n < e; ++n) s0 += e2[(long)n * 64 + lane];
    float sum = (s0 + s1) + (s2 + s3);
    ge[(long)g * 64 + lane] = sum / fmaxf((float)(e - s), 1.f);
  }
}

// ---------------- pair MLP ----------------
#define PPB 16
__global__ __launch_bounds__(256) void pair_mlp(const float* __restrict__ ge,
                                                const int* __restrict__ dp,
                                                const float* __restrict__ Wr1,
                                                const float* __restrict__ br1,
                                                const float* __restrict__ Wr2,
                                                const float* __restrict__ br2,
                                                float* __restrict__ out, int P) {
  __shared__ float feat[PPB][128];
  __shared__ int pidx[2][PPB];
  __shared__ float red[4][PPB];
  int tid = threadIdx.x;
  int base = blockIdx.x * PPB;
  if (tid < PPB) {
    int p = base + tid;
    pidx[0][tid] = (p < P) ? dp[p] : 0;
    pidx[1][tid] = (p < P) ? dp[P + p] : 0;
  }
  __syncthreads();
#pragma unroll
  for (int i = 0; i < 8; ++i) {
    int f = tid + i * 256;
    int p = f >> 7;
    int k = f & 127;
    int g = (k < 64) ? pidx[0][p] : pidx[1][p];
    feat[p][k] = ge[(long)g * 64 + (k & 63)];
  }
  __syncthreads();
  int j = tid;
  float w2 = Wr2[j];
  float b1v = br1[j];
  float acc[PPB];
#pragma unroll
  for (int p = 0; p < PPB; ++p) acc[p] = 0.f;
  for (int k4 = 0; k4 < 128; k4 += 4) {
    float w0 = Wr1[(k4 + 0) * 256 + j];
    float w1 = Wr1[(k4 + 1) * 256 + j];
    float wv2 = Wr1[(k4 + 2) * 256 + j];
    float w3 = Wr1[(k4 + 3) * 256 + j];
#pragma unroll
    for (int p = 0; p < PPB; ++p) {
      float4 f = *(const float4*)&feat[p][k4];
      acc[p] = fmaf(f.x, w0, acc[p]);
      acc[p] = fmaf(f.y, w1, acc[p]);
      acc[p] = fmaf(f.z, wv2, acc[p]);
      acc[p] = fmaf(f.w, w3, acc[p]);
    }
  }
  int wv = tid >> 6;
#pragma unroll
  for (int p = 0; p < PPB; ++p) {
    float hid = fmaxf(acc[p] + b1v, 0.f);
    float v = hid * w2;
    for (int o = 32; o > 0; o >>= 1) v += __shfl_down(v, o, 64);
    if ((tid & 63) == 0) red[wv][p] = v;
  }
  __syncthreads();
  if (tid < PPB) {
    int p = base + tid;
    if (p < P) out[p] = red[0][tid] + red[1][tid] + red[2][tid] + red[3][tid] + br2[0];
  }
}

extern "C" void kernel_launch(void* const* d_in, const int* in_sizes, int n_in,
                              void* d_out, int out_size, void* d_ws, size_t ws_size,
                              hipStream_t stream) {
  const float* x = (const float*)d_in[0];
  const int* ei = (const int*)d_in[1];
  const int* batch = (const int*)d_in[2];
  const int* dp = (const int*)d_in[3];
  const float* W1 = (const float*)d_in[4];
  const float* b1 = (const float*)d_in[5];
  const float* W2 = (const float*)d_in[6];
  const float* b2 = (const float*)d_in[7];
  const float* Wr1 = (const float*)d_in[8];
  const float* br1 = (const float*)d_in[9];
  const float* Wr2 = (const float*)d_in[10];
  const float* br2 = (const float*)d_in[11];
  float* out = (float*)d_out;

  int N = in_sizes[0] / 64;
  int E = in_sizes[1] / 2;
  int P = in_sizes[3] / 2;
  int G = N_GRAPHS;
  const int* src = ei;
  const int* dstp = ei + E;

  char* ws = (char*)d_ws;
  size_t o = 0;
  auto alloc = [&](size_t bytes) {
    void* p = ws + o;
    o += (bytes + 255) & ~(size_t)255;
    return p;
  };
  float* isq = (float*)alloc((size_t)N * 4);
  int* cnt = (int*)alloc((size_t)N * 4);
  int* rs = (int*)alloc((size_t)(N + 1) * 4);
  int* ptr = (int*)alloc((size_t)N * 4);
  int* bsum = (int*)alloc(1024 * 4);
  int* goff = (int*)alloc((size_t)(G + 1) * 4);
  int* csr = (int*)alloc((size_t)(E + 8) * 4);  // +pad: 3-ahead overread safe
  float* hbuf = (float*)alloc((size_t)N * 64 * 4);
  float* abuf = (float*)alloc((size_t)N * 64 * 4);
  float* ge = (float*)alloc((size_t)G * 64 * 4);

  hipMemsetAsync(cnt, 0, (size_t)N * 4, stream);
  count_in_deg<<<2048, 256, 0, stream>>>(dstp, cnt, E);
  inv_sqrt_deg<<<(N + 255) / 256, 256, 0, stream>>>(cnt, isq, N);

  // CSR build
  int nb = (N + SCAN_CHUNK - 1) / SCAN_CHUNK;
  scan1<<<nb, 256, 0, stream>>>(cnt, rs, bsum, N);
  scan2<<<1, 256, 0, stream>>>(bsum, nb);
  scan3<<<(N + 1 + 255) / 256, 256, 0, stream>>>(rs, bsum, ptr, N + 1);
  csr_fill<<<2048, 256, 0, stream>>>(src, dstp, ptr, csr, E);

  int tiles = (N + 63) / 64;
  int gblocks = (N + 15) / 16;  // 4 waves/block, 4 dst/wave (one per 16-lane group)
  // conv1
  gemm_n64<<<tiles, 256, 0, stream>>>(x, W1, isq, hbuf, N);
  gather_conv<<<gblocks, 256, 0, stream>>>(hbuf, csr, rs, isq, b1, abuf, N);
  // conv2
  gemm_n64<<<tiles, 256, 0, stream>>>(abuf, W2, isq, hbuf, N);
  gather_conv<<<gblocks, 256, 0, stream>>>(hbuf, csr, rs, isq, b2, abuf, N);
  // pool
  seg_offsets<<<(N + 255) / 256, 256, 0, stream>>>(batch, goff, N, G);
  pool_mean<<<2048, 256, 0, stream>>>(abuf, goff, ge, G);
  // pair MLP
  pair_mlp<<<(P + PPB - 1) / PPB, 256, 0, stream>>>(ge, dp, Wr1, br1, Wr2, br2, out, P);
}

// Round 8
// 612.243 us; speedup vs baseline: 1.1563x; 1.1563x over previous
//
#include <hip/hip_runtime.h>
#include <cstdint>

#define N_GRAPHS 20000
#define SCAN_CHUNK 2048
#define NBLK 512  // blocks for bucket hist/scatter

__global__ void inv_sqrt_deg(const int* __restrict__ cnt, float* __restrict__ isq, int N) {
  int i = blockIdx.x * blockDim.x + threadIdx.x;
  if (i < N) isq[i] = rsqrtf((float)(cnt[i] + 1));
}

// ---------------- prefix scan (exclusive) of in[M] -> out[M+1] ----------------
__global__ __launch_bounds__(256) void scan1(const int* __restrict__ in, int* __restrict__ out,
                                             int* __restrict__ bsum, int M) {
  __shared__ int lds[256];
  int t = threadIdx.x;
  int base = blockIdx.x * SCAN_CHUNK + t * 8;
  int v[8];
  int s = 0;
#pragma unroll
  for (int i = 0; i < 8; ++i) {
    v[i] = (base + i < M) ? in[base + i] : 0;
    s += v[i];
  }
  lds[t] = s;
  __syncthreads();
  for (int off = 1; off < 256; off <<= 1) {
    int x = (t >= off) ? lds[t - off] : 0;
    __syncthreads();
    lds[t] += x;
    __syncthreads();
  }
  if (t == 255) bsum[blockIdx.x] = lds[255];
  int run = (t > 0) ? lds[t - 1] : 0;
#pragma unroll
  for (int i = 0; i < 8; ++i) {
    if (base + i <= M) out[base + i] = run;
    run += v[i];
  }
}

__global__ __launch_bounds__(256) void scan2(int* __restrict__ bsum, int nb) {
  __shared__ int lds[256];
  int t = threadIdx.x;
  lds[t] = (t < nb) ? bsum[t] : 0;
  __syncthreads();
  for (int off = 1; off < 256; off <<= 1) {
    int x = (t >= off) ? lds[t - off] : 0;
    __syncthreads();
    lds[t] += x;
    __syncthreads();
  }
  if (t < nb) bsum[t] = (t > 0) ? lds[t - 1] : 0;  // exclusive
}

__global__ void scan3(int* __restrict__ out, const int* __restrict__ bsum, int Mp1) {
  int i = blockIdx.x * blockDim.x + threadIdx.x;
  if (i < Mp1) out[i] += bsum[i / SCAN_CHUNK];
}

// ---------------- P1: per-block bucket histogram (bucket = dst >> 10) ----------------
__global__ __launch_bounds__(256) void bucket_hist(const int* __restrict__ dst,
                                                   int* __restrict__ bcnt, int E, int nbuck) {
  __shared__ int h[512];
  for (int i = threadIdx.x; i < 512; i += 256) h[i] = 0;
  __syncthreads();
  int per = (E + NBLK - 1) / NBLK;
  int s = blockIdx.x * per;
  int e = min(s + per, E);
  for (int i = s + threadIdx.x; i < e; i += 256) atomicAdd(&h[dst[i] >> 10], 1);
  __syncthreads();
  for (int b = threadIdx.x; b < nbuck; b += 256) bcnt[(long)b * NBLK + blockIdx.x] = h[b];
}

// ---------------- P2: scatter edges into bucket-ordered arrays ----------------
__global__ __launch_bounds__(256) void bucket_scatter(const int* __restrict__ src,
                                                      const int* __restrict__ dst,
                                                      const int* __restrict__ bbase,
                                                      int* __restrict__ sdst,
                                                      int* __restrict__ ssrc, int E, int nbuck) {
  __shared__ int h[512];
  for (int b = threadIdx.x; b < nbuck; b += 256) h[b] = bbase[(long)b * NBLK + blockIdx.x];
  __syncthreads();
  int per = (E + NBLK - 1) / NBLK;
  int s = blockIdx.x * per;
  int e = min(s + per, E);
  for (int i = s + threadIdx.x; i < e; i += 256) {
    int d = dst[i];
    int pos = atomicAdd(&h[d >> 10], 1);
    sdst[pos] = d;
    ssrc[pos] = src[i];
  }
}

// ---------------- P3a: per-bucket node histogram -> cnt (coalesced, no global atomics) -------
__global__ __launch_bounds__(256) void node_hist(const int* __restrict__ sdst,
                                                 const int* __restrict__ bbase,
                                                 int* __restrict__ cnt, int E, int nbuck, int N) {
  __shared__ int h[1024];
  int b = blockIdx.x;
  int n0 = b << 10;
  int nn = min(1024, N - n0);
  for (int i = threadIdx.x; i < nn; i += 256) h[i] = 0;
  __syncthreads();
  int s = bbase[(long)b * NBLK];
  int e = (b + 1 < nbuck) ? bbase[(long)(b + 1) * NBLK] : E;
  for (int i = s + threadIdx.x; i < e; i += 256) atomicAdd(&h[sdst[i] - n0], 1);
  __syncthreads();
  for (int i = threadIdx.x; i < nn; i += 256) cnt[n0 + i] = h[i];
}

// ---------------- P3c: per-bucket CSR write (LDS ranks, contiguous csr region) ----------------
__global__ __launch_bounds__(256) void csr_write(const int* __restrict__ sdst,
                                                 const int* __restrict__ ssrc,
                                                 const int* __restrict__ bbase,
                                                 const int* __restrict__ rs,
                                                 int* __restrict__ csr, int E, int nbuck, int N) {
  __shared__ int h[1024];
  int b = blockIdx.x;
  int n0 = b << 10;
  int nn = min(1024, N - n0);
  for (int i = threadIdx.x; i < nn; i += 256) h[i] = rs[n0 + i];
  __syncthreads();
  int s = bbase[(long)b * NBLK];
  int e = (b + 1 < nbuck) ? bbase[(long)(b + 1) * NBLK] : E;
  for (int i = s + threadIdx.x; i < e; i += 256) {
    int d = sdst[i];
    int pos = atomicAdd(&h[d - n0], 1);
    csr[pos] = ssrc[i];
  }
}

// ---------------- node GEMM + row scale: out[r,:] = (in[r,:] @ W) * isq[r] ----------------
__global__ __launch_bounds__(256) void gemm_n64(const float* __restrict__ in,
                                                const float* __restrict__ W,
                                                const float* __restrict__ isq,
                                                float* __restrict__ out, int N) {
  __shared__ float Wl[64 * 64];
  __shared__ float Rl[64 * 65];
  int tid = threadIdx.x;
#pragma unroll
  for (int v = 0; v < 4; ++v) {
    int u = tid + v * 256;
    *(float4*)&Wl[u * 4] = *(const float4*)&W[u * 4];
  }
  long base_row = (long)blockIdx.x * 64;
#pragma unroll
  for (int v = 0; v < 4; ++v) {
    int u = tid + v * 256;
    int r = u >> 4;
    int k = (u & 15) * 4;
    long row = base_row + r;
    float4 val = make_float4(0.f, 0.f, 0.f, 0.f);
    if (row < N) val = *(const float4*)&in[row * 64 + k];
    *(float4*)&Rl[r * 65 + k] = val;
  }
  __syncthreads();
  int r = tid >> 2;
  int c0 = (tid & 3) * 16;
  float acc[16];
#pragma unroll
  for (int j = 0; j < 16; ++j) acc[j] = 0.f;
#pragma unroll 4
  for (int k = 0; k < 64; ++k) {
    float a = Rl[r * 65 + k];
#pragma unroll
    for (int j = 0; j < 16; ++j) acc[j] += a * Wl[k * 64 + c0 + j];
  }
  long row = base_row + r;
  if (row < N) {
    float sc = isq[row];
#pragma unroll
    for (int v = 0; v < 4; ++v) {
      *(float4*)&out[row * 64 + c0 + v * 4] =
          make_float4(acc[v * 4] * sc, acc[v * 4 + 1] * sc, acc[v * 4 + 2] * sc,
                      acc[v * 4 + 3] * sc);
    }
  }
}

// ------- gather conv: out[d] = relu(isq[d]*(sum_{s in N(d)} hp[s] + hp[d]) + b) -------
__global__ __launch_bounds__(256) void gather_conv(const float* __restrict__ hp,
                                                   const int* __restrict__ csr,
                                                   const int* __restrict__ rs,
                                                   const float* __restrict__ isq,
                                                   const float* __restrict__ bias,
                                                   float* __restrict__ out, int N) {
  int lane = threadIdx.x & 63;
  int sub = lane & 15;   // channel quad within row
  int grp = lane >> 4;   // dst group within wave
  int wid = (blockIdx.x * blockDim.x + threadIdx.x) >> 6;
  float4 bv = *(const float4*)&bias[sub * 4];
  long d0 = (long)wid * 4;
  if (d0 >= N) return;
  int d = (int)d0 + grp;
  bool vd = d < N;
  int dd = vd ? d : N - 1;
  int jj = rs[dd];
  int je = vd ? rs[dd + 1] : jj;
  float4 ac = make_float4(0.f, 0.f, 0.f, 0.f);
  if (vd) ac = *(const float4*)&hp[(long)dd * 64 + sub * 4];
  while (__any(jj < je)) {
    bool a0 = jj < je;
    bool a1 = jj + 1 < je;
    bool a2 = jj + 2 < je;
    bool a3 = jj + 3 < je;
    int s0 = csr[jj];
    int s1 = csr[jj + 1];
    int s2 = csr[jj + 2];
    int s3 = csr[jj + 3];
    float4 v0 = make_float4(0.f, 0.f, 0.f, 0.f);
    float4 v1 = make_float4(0.f, 0.f, 0.f, 0.f);
    float4 v2 = make_float4(0.f, 0.f, 0.f, 0.f);
    float4 v3 = make_float4(0.f, 0.f, 0.f, 0.f);
    if (a0) v0 = *(const float4*)&hp[(long)s0 * 64 + sub * 4];
    if (a1) v1 = *(const float4*)&hp[(long)s1 * 64 + sub * 4];
    if (a2) v2 = *(const float4*)&hp[(long)s2 * 64 + sub * 4];
    if (a3) v3 = *(const float4*)&hp[(long)s3 * 64 + sub * 4];
    ac.x += (v0.x + v1.x) + (v2.x + v3.x);
    ac.y += (v0.y + v1.y) + (v2.y + v3.y);
    ac.z += (v0.z + v1.z) + (v2.z + v3.z);
    ac.w += (v0.w + v1.w) + (v2.w + v3.w);
    jj += 4;
  }
  if (vd) {
    float id = isq[d];
    float4 r;
    r.x = fmaxf(fmaf(ac.x, id, bv.x), 0.f);
    r.y = fmaxf(fmaf(ac.y, id, bv.y), 0.f);
    r.z = fmaxf(fmaf(ac.z, id, bv.z), 0.f);
    r.w = fmaxf(fmaf(ac.w, id, bv.w), 0.f);
    *(float4*)&out[(long)d * 64 + sub * 4] = r;
  }
}

// ---------------- graph segment offsets from sorted batch_idx ----------------
__global__ void seg_offsets(const int* __restrict__ batch, int* __restrict__ off, int N, int G) {
  int i = blockIdx.x * blockDim.x + threadIdx.x;
  if (i >= N) return;
  int b = batch[i];
  if (i == 0) {
    for (int g = 0; g <= b; ++g) off[g] = 0;
  } else {
    int pb = batch[i - 1];
    for (int g = pb + 1; g <= b; ++g) off[g] = i;
  }
  if (i == N - 1) {
    for (int g = b + 1; g <= G; ++g) off[g] = N;
  }
}

// ---------------- mean pool: wave per graph, 4 independent partial sums ----------------
__global__ void pool_mean(const float* __restrict__ e2, const int* __restrict__ off,
                          float* __restrict__ ge, int G) {
  int lane = threadIdx.x & 63;
  int wid = (blockIdx.x * blockDim.x + threadIdx.x) >> 6;
  int nw = (gridDim.x * blockDim.x) >> 6;
  for (int g = wid; g < G; g += nw) {
    int s = off[g];
    int e = off[g + 1];
    float s0 = 0.f, s1 = 0.f, s2 = 0.f, s3 = 0.f;
    int n = s;
    for (; n + 3 < e; n += 4) {
      s0 += e2[(long)n * 64 + lane];
      s1 += e2[(long)(n + 1) * 64 + lane];
      s2 += e2[(long)(n + 2) * 64 + lane];
      s3 += e2[(long)(n + 3) * 64 + lane];
    }
    for (; n < e; ++n) s0 += e2[(long)n * 64 + lane];
    float sum = (s0 + s1) + (s2 + s3);
    ge[(long)g * 64 + lane] = sum / fmaxf((float)(e - s), 1.f);
  }
}

// ---------------- pair MLP ----------------
#define PPB 16
__global__ __launch_bounds__(256) void pair_mlp(const float* __restrict__ ge,
                                                const int* __restrict__ dp,
                                                const float* __restrict__ Wr1,
                                                const float* __restrict__ br1,
                                                const float* __restrict__ Wr2,
                                                const float* __restrict__ br2,
                                                float* __restrict__ out, int P) {
  __shared__ float feat[PPB][128];
  __shared__ int pidx[2][PPB];
  __shared__ float red[4][PPB];
  int tid = threadIdx.x;
  int base = blockIdx.x * PPB;
  if (tid < PPB) {
    int p = base + tid;
    pidx[0][tid] = (p < P) ? dp[p] : 0;
    pidx[1][tid] = (p < P) ? dp[P + p] : 0;
  }
  __syncthreads();
#pragma unroll
  for (int i = 0; i < 8; ++i) {
    int f = tid + i * 256;
    int p = f >> 7;
    int k = f & 127;
    int g = (k < 64) ? pidx[0][p] : pidx[1][p];
    feat[p][k] = ge[(long)g * 64 + (k & 63)];
  }
  __syncthreads();
  int j = tid;
  float w2 = Wr2[j];
  float b1v = br1[j];
  float acc[PPB];
#pragma unroll
  for (int p = 0; p < PPB; ++p) acc[p] = 0.f;
  for (int k4 = 0; k4 < 128; k4 += 4) {
    float w0 = Wr1[(k4 + 0) * 256 + j];
    float w1 = Wr1[(k4 + 1) * 256 + j];
    float wv2 = Wr1[(k4 + 2) * 256 + j];
    float w3 = Wr1[(k4 + 3) * 256 + j];
#pragma unroll
    for (int p = 0; p < PPB; ++p) {
      float4 f = *(const float4*)&feat[p][k4];
      acc[p] = fmaf(f.x, w0, acc[p]);
      acc[p] = fmaf(f.y, w1, acc[p]);
      acc[p] = fmaf(f.z, wv2, acc[p]);
      acc[p] = fmaf(f.w, w3, acc[p]);
    }
  }
  int wv = tid >> 6;
#pragma unroll
  for (int p = 0; p < PPB; ++p) {
    float hid = fmaxf(acc[p] + b1v, 0.f);
    float v = hid * w2;
    for (int o = 32; o > 0; o >>= 1) v += __shfl_down(v, o, 64);
    if ((tid & 63) == 0) red[wv][p] = v;
  }
  __syncthreads();
  if (tid < PPB) {
    int p = base + tid;
    if (p < P) out[p] = red[0][tid] + red[1][tid] + red[2][tid] + red[3][tid] + br2[0];
  }
}

extern "C" void kernel_launch(void* const* d_in, const int* in_sizes, int n_in,
                              void* d_out, int out_size, void* d_ws, size_t ws_size,
                              hipStream_t stream) {
  const float* x = (const float*)d_in[0];
  const int* ei = (const int*)d_in[1];
  const int* batch = (const int*)d_in[2];
  const int* dp = (const int*)d_in[3];
  const float* W1 = (const float*)d_in[4];
  const float* b1 = (const float*)d_in[5];
  const float* W2 = (const float*)d_in[6];
  const float* b2 = (const float*)d_in[7];
  const float* Wr1 = (const float*)d_in[8];
  const float* br1 = (const float*)d_in[9];
  const float* Wr2 = (const float*)d_in[10];
  const float* br2 = (const float*)d_in[11];
  float* out = (float*)d_out;

  int N = in_sizes[0] / 64;
  int E = in_sizes[1] / 2;
  int P = in_sizes[3] / 2;
  int G = N_GRAPHS;
  const int* src = ei;
  const int* dstp = ei + E;

  int nbuck = (N + 1023) >> 10;        // <= 512
  long M = (long)nbuck * NBLK;         // bucket-count matrix size (<= 262144)

  char* ws = (char*)d_ws;
  size_t o = 0;
  auto alloc = [&](size_t bytes) {
    void* p = ws + o;
    o += (bytes + 255) & ~(size_t)255;
    return p;
  };
  float* isq = (float*)alloc((size_t)N * 4);
  int* cnt = (int*)alloc((size_t)N * 4);
  int* rs = (int*)alloc((size_t)(N + 1) * 4);
  int* bsum = (int*)alloc(1024 * 4);
  int* goff = (int*)alloc((size_t)(G + 1) * 4);
  int* bcnt = (int*)alloc((size_t)(M + 1) * 4);  // scan output in-place capable
  int* sdst = (int*)alloc((size_t)E * 4);
  int* ssrc = (int*)alloc((size_t)E * 4);
  int* csr = (int*)alloc((size_t)(E + 8) * 4);  // +pad: 3-ahead overread safe
  float* hbuf = (float*)alloc((size_t)N * 64 * 4);
  float* abuf = (float*)alloc((size_t)N * 64 * 4);
  float* ge = (float*)alloc((size_t)G * 64 * 4);

  // --- CSR build, atomic-free at global scope ---
  bucket_hist<<<NBLK, 256, 0, stream>>>(dstp, bcnt, E, nbuck);
  int nbA = (int)((M + SCAN_CHUNK - 1) / SCAN_CHUNK);
  scan1<<<nbA, 256, 0, stream>>>(bcnt, bcnt, bsum, (int)M);  // in-place exclusive scan
  scan2<<<1, 256, 0, stream>>>(bsum, nbA);
  scan3<<<(int)((M + 1 + 255) / 256), 256, 0, stream>>>(bcnt, bsum, (int)(M + 1));
  bucket_scatter<<<NBLK, 256, 0, stream>>>(src, dstp, bcnt, sdst, ssrc, E, nbuck);
  node_hist<<<nbuck, 256, 0, stream>>>(sdst, bcnt, cnt, E, nbuck, N);
  inv_sqrt_deg<<<(N + 255) / 256, 256, 0, stream>>>(cnt, isq, N);
  int nbB = (N + SCAN_CHUNK - 1) / SCAN_CHUNK;
  scan1<<<nbB, 256, 0, stream>>>(cnt, rs, bsum, N);
  scan2<<<1, 256, 0, stream>>>(bsum, nbB);
  scan3<<<(N + 1 + 255) / 256, 256, 0, stream>>>(rs, bsum, N + 1);
  csr_write<<<nbuck, 256, 0, stream>>>(sdst, ssrc, bcnt, rs, csr, E, nbuck, N);

  int tiles = (N + 63) / 64;
  int gblocks = (N + 15) / 16;  // 4 waves/block, 4 dst/wave (one per 16-lane group)
  // conv1
  gemm_n64<<<tiles, 256, 0, stream>>>(x, W1, isq, hbuf, N);
  gather_conv<<<gblocks, 256, 0, stream>>>(hbuf, csr, rs, isq, b1, abuf, N);
  // conv2
  gemm_n64<<<tiles, 256, 0, stream>>>(abuf, W2, isq, hbuf, N);
  gather_conv<<<gblocks, 256, 0, stream>>>(hbuf, csr, rs, isq, b2, abuf, N);
  // pool
  seg_offsets<<<(N + 255) / 256, 256, 0, stream>>>(batch, goff, N, G);
  pool_mean<<<2048, 256, 0, stream>>>(abuf, goff, ge, G);
  // pair MLP
  pair_mlp<<<(P + PPB - 1) / PPB, 256, 0, stream>>>(ge, dp, Wr1, br1, Wr2, br2, out, P);
}